// Round 3
// baseline (535.934 us; speedup 1.0000x reference)
//
#include <hip/hip_runtime.h>

// FNO3d forward, MI355X. Correctness-first naive staged pipeline.
// B=8, C=8 (width), D=H=W=64, modes=4. Separable partial DFTs:
// only kx,ky in {0..3,60..63}, kz in {0..3} survive the spectral conv.
//
// Stages per layer: fwdW (x->A), fwdH (A->Bh), fwdD (Bh->C), mix (C->O),
// invD (O->P), invH (P->Q), pt (Q,x->x in-place, conv+gelu).
// Buffer reuse: Q overlays A (A dead after fwdH); P overlays Bh.

#define TWO_PI_OVER_64 0.09817477042468103

__device__ __forceinline__ float gelu_f(float x) {
    float inner = 0.7978845608028654f * (x + 0.044715f * x * x * x);
    return 0.5f * x * (1.0f + tanhf(inner));
}

#define BUILD_TW() \
    __shared__ float twc[64], tws[64]; \
    if (threadIdx.x < 64) { \
        double a_ = TWO_PI_OVER_64 * (double)threadIdx.x; \
        twc[threadIdx.x] = (float)cos(a_); tws[threadIdx.x] = (float)sin(a_); \
    } \
    __syncthreads();

// x[b][o][d][h][w] = fc0_b[o] + sum_c u[b][c][d][h][w]*fc0_w[o][c]
// 2,097,152 threads (one per b,d,h,w point; all 8 o in-thread)
__global__ __launch_bounds__(256) void k_lift(
    const float* __restrict__ u, const float* __restrict__ w,
    const float* __restrict__ bv, float* __restrict__ x)
{
    int p = blockIdx.x * 256 + threadIdx.x;
    int b = p >> 18, rem = p & 262143;
    float u0 = u[(size_t)(b * 3 + 0) * 262144 + rem];
    float u1 = u[(size_t)(b * 3 + 1) * 262144 + rem];
    float u2 = u[(size_t)(b * 3 + 2) * 262144 + rem];
    #pragma unroll
    for (int o = 0; o < 8; ++o) {
        float v = bv[o] + u0 * w[o * 3 + 0] + u1 * w[o * 3 + 1] + u2 * w[o * 3 + 2];
        x[(size_t)(b * 8 + o) * 262144 + rem] = v;
    }
}

// A[b][c][dx][dy][kz] = sum_w x[b][c][dx][dy][w] * e^{-2pi i kz w/64}, kz=0..3
// 262,144 threads (one per b,c,dx,dy)
__global__ __launch_bounds__(256) void k_fwdW(
    const float* __restrict__ x, float2* __restrict__ A)
{
    BUILD_TW();
    int g = blockIdx.x * 256 + threadIdx.x;
    int dy = g & 63, dx = (g >> 6) & 63, c = (g >> 12) & 7, b = g >> 15;
    const float* row = x + (size_t)(b * 8 + c) * 262144 + dx * 4096 + dy * 64;
    float ar[4] = {0.f, 0.f, 0.f, 0.f}, ai[4] = {0.f, 0.f, 0.f, 0.f};
    for (int w = 0; w < 64; ++w) {
        float v = row[w];
        ar[0] += v;
        #pragma unroll
        for (int k = 1; k < 4; ++k) {
            int ti = (k * w) & 63;
            ar[k] += v * twc[ti]; ai[k] -= v * tws[ti];
        }
    }
    float2* Ao = A + ((size_t)(b * 8 + c) * 4096 + dx * 64 + dy) * 4;
    #pragma unroll
    for (int k = 0; k < 4; ++k) Ao[k] = make_float2(ar[k], ai[k]);
}

// Bh[b][c][dx][ky][kz] = sum_dy A[b][c][dx][dy][kz] * e^{-2pi i kyv dy/64}
// ky index 0..7 -> freq {0..3,60..63}. 32,768 threads (4 kz in-thread)
__global__ __launch_bounds__(256) void k_fwdH(
    const float2* __restrict__ A, float2* __restrict__ Bh)
{
    BUILD_TW();
    int g = blockIdx.x * 256 + threadIdx.x;
    int ky = g & 7, dx = (g >> 3) & 63, c = (g >> 9) & 7, b = g >> 12;
    int kyv = ky < 4 ? ky : ky + 56;
    const float2* Ab = A + ((size_t)(b * 8 + c) * 4096 + dx * 64) * 4;
    float re[4] = {0.f,0.f,0.f,0.f}, im[4] = {0.f,0.f,0.f,0.f};
    for (int dy = 0; dy < 64; ++dy) {
        int ti = (kyv * dy) & 63;
        float cc = twc[ti], ss = tws[ti];
        #pragma unroll
        for (int kz = 0; kz < 4; ++kz) {
            float2 a = Ab[dy * 4 + kz];
            re[kz] += a.x * cc + a.y * ss;   // * e^{-i phi}
            im[kz] += a.y * cc - a.x * ss;
        }
    }
    float2* Bo = Bh + (((size_t)(b * 8 + c) * 64 + dx) * 8 + ky) * 4;
    #pragma unroll
    for (int kz = 0; kz < 4; ++kz) Bo[kz] = make_float2(re[kz], im[kz]);
}

// C[b][c][kx][ky][kz] = sum_dx Bh[b][c][dx][ky][kz] * e^{-2pi i kxv dx/64}
// 4,096 threads
__global__ __launch_bounds__(256) void k_fwdD(
    const float2* __restrict__ Bh, float2* __restrict__ C)
{
    BUILD_TW();
    int g = blockIdx.x * 256 + threadIdx.x;
    int ky = g & 7, kx = (g >> 3) & 7, c = (g >> 6) & 7, b = g >> 9;
    int kxv = kx < 4 ? kx : kx + 56;
    float re[4] = {0.f,0.f,0.f,0.f}, im[4] = {0.f,0.f,0.f,0.f};
    for (int dx = 0; dx < 64; ++dx) {
        int ti = (kxv * dx) & 63;
        float cc = twc[ti], ss = tws[ti];
        #pragma unroll
        for (int kz = 0; kz < 4; ++kz) {
            float2 v = Bh[(((size_t)(b * 8 + c) * 64 + dx) * 8 + ky) * 4 + kz];
            re[kz] += v.x * cc + v.y * ss;
            im[kz] += v.y * cc - v.x * ss;
        }
    }
    #pragma unroll
    for (int kz = 0; kz < 4; ++kz)
        C[(((size_t)(b * 8 + c) * 8 + kx) * 8 + ky) * 4 + kz] = make_float2(re[kz], im[kz]);
}

// O[b][o][kx][ky][kz] = sum_i C[b][i][kx][ky][kz] * w_corner[i][o][kx&3][ky&3][kz]
// 16,384 threads
__global__ __launch_bounds__(256) void k_mix(
    const float2* __restrict__ C,
    const float2* __restrict__ w1, const float2* __restrict__ w2,
    const float2* __restrict__ w3, const float2* __restrict__ w4,
    float2* __restrict__ O)
{
    int gid = blockIdx.x * 256 + threadIdx.x;
    int kz = gid & 3, ky = (gid >> 2) & 7, kx = (gid >> 5) & 7;
    int o = (gid >> 8) & 7, b = gid >> 11;
    const float2* wsel = (kx < 4) ? ((ky < 4) ? w1 : w3) : ((ky < 4) ? w2 : w4);
    int kxw = kx & 3, kyw = ky & 3;
    float re = 0.f, im = 0.f;
    for (int i = 0; i < 8; ++i) {
        float2 cv = C[(((size_t)(b * 8 + i) * 8 + kx) * 8 + ky) * 4 + kz];
        float2 wv = wsel[(((size_t)(i * 8 + o) * 4 + kxw) * 4 + kyw) * 4 + kz];
        re += cv.x * wv.x - cv.y * wv.y;
        im += cv.x * wv.y + cv.y * wv.x;
    }
    O[gid] = make_float2(re, im);
}

// P[b][o][dx][ky][kz] = sum_kx O[b][o][kx][ky][kz] * e^{+2pi i kxv dx/64}
// 32,768 threads
__global__ __launch_bounds__(256) void k_invD(
    const float2* __restrict__ O, float2* __restrict__ P)
{
    BUILD_TW();
    int g = blockIdx.x * 256 + threadIdx.x;
    int ky = g & 7, dx = (g >> 3) & 63, o = (g >> 9) & 7, b = g >> 12;
    float re[4] = {0.f,0.f,0.f,0.f}, im[4] = {0.f,0.f,0.f,0.f};
    #pragma unroll
    for (int kxi = 0; kxi < 8; ++kxi) {
        int kxv = kxi < 4 ? kxi : kxi + 56;
        int ti = (kxv * dx) & 63;
        float cc = twc[ti], ss = tws[ti];
        #pragma unroll
        for (int kz = 0; kz < 4; ++kz) {
            float2 v = O[(((size_t)(b * 8 + o) * 8 + kxi) * 8 + ky) * 4 + kz];
            re[kz] += v.x * cc - v.y * ss;   // * e^{+i phi}
            im[kz] += v.y * cc + v.x * ss;
        }
    }
    #pragma unroll
    for (int kz = 0; kz < 4; ++kz)
        P[(((size_t)(b * 8 + o) * 64 + dx) * 8 + ky) * 4 + kz] = make_float2(re[kz], im[kz]);
}

// Q[b][o][dx][dy][kz] = sum_ky P[b][o][dx][ky][kz] * e^{+2pi i kyv dy/64}
// 262,144 threads
__global__ __launch_bounds__(256) void k_invH(
    const float2* __restrict__ P, float2* __restrict__ Q)
{
    BUILD_TW();
    int g = blockIdx.x * 256 + threadIdx.x;
    int dy = g & 63, dx = (g >> 6) & 63, o = (g >> 12) & 7, b = g >> 15;
    float re[4] = {0.f,0.f,0.f,0.f}, im[4] = {0.f,0.f,0.f,0.f};
    #pragma unroll
    for (int kyi = 0; kyi < 8; ++kyi) {
        int kyv = kyi < 4 ? kyi : kyi + 56;
        int ti = (kyv * dy) & 63;
        float cc = twc[ti], ss = tws[ti];
        #pragma unroll
        for (int kz = 0; kz < 4; ++kz) {
            float2 v = P[(((size_t)(b * 8 + o) * 64 + dx) * 8 + kyi) * 4 + kz];
            re[kz] += v.x * cc - v.y * ss;
            im[kz] += v.y * cc + v.x * ss;
        }
    }
    float2* Qo = Q + (size_t)(b * 8 + o) * 16384 + dx * 256 + dy * 4;
    #pragma unroll
    for (int kz = 0; kz < 4; ++kz) Qo[kz] = make_float2(re[kz], im[kz]);
}

// Pointwise: x[o] = (maybe gelu)( irfftW(Q)[o] + conv(x)[o] + cb[o] )
// One thread owns ALL 8 channels of 4 w-points -> in-place x update is safe.
// 524,288 threads
__global__ __launch_bounds__(256) void k_pt(
    float* __restrict__ x, const float2* __restrict__ Q,
    const float* __restrict__ cw, const float* __restrict__ cb, int do_gelu)
{
    BUILD_TW();
    int g = blockIdx.x * 256 + threadIdx.x;
    int wq = g & 15, dy = (g >> 4) & 63, dx = (g >> 10) & 63, b = g >> 16;
    float c1[4], s1[4], c2[4], s2[4], c3[4], s3[4];
    #pragma unroll
    for (int j = 0; j < 4; ++j) {
        int w = wq * 4 + j;
        c1[j] = twc[w & 63];        s1[j] = tws[w & 63];
        c2[j] = twc[(2 * w) & 63];  s2[j] = tws[(2 * w) & 63];
        c3[j] = twc[(3 * w) & 63];  s3[j] = tws[(3 * w) & 63];
    }
    float xin[8][4];
    #pragma unroll
    for (int c = 0; c < 8; ++c) {
        float4 xv = *(const float4*)&x[(size_t)(b * 8 + c) * 262144 + dx * 4096 + dy * 64 + wq * 4];
        xin[c][0] = xv.x; xin[c][1] = xv.y; xin[c][2] = xv.z; xin[c][3] = xv.w;
    }
    const float invN3 = 1.0f / 262144.0f;
    float outv[8][4];
    #pragma unroll
    for (int o = 0; o < 8; ++o) {
        const float2* q = Q + (size_t)(b * 8 + o) * 16384 + dx * 256 + dy * 4;
        float2 q0 = q[0], q1 = q[1], q2 = q[2], q3 = q[3];
        #pragma unroll
        for (int j = 0; j < 4; ++j) {
            // irfft along W: DC bin contributes its real part only (c2r semantics)
            float x1 = q0.x + 2.f * (q1.x * c1[j] - q1.y * s1[j]
                                   + q2.x * c2[j] - q2.y * s2[j]
                                   + q3.x * c3[j] - q3.y * s3[j]);
            x1 *= invN3;
            float x2 = cb[o];
            #pragma unroll
            for (int c = 0; c < 8; ++c) x2 += cw[o * 8 + c] * xin[c][j];
            float v = x1 + x2;
            outv[o][j] = do_gelu ? gelu_f(v) : v;
        }
    }
    #pragma unroll
    for (int o = 0; o < 8; ++o)
        *(float4*)&x[(size_t)(b * 8 + o) * 262144 + dx * 4096 + dy * 64 + wq * 4] =
            make_float4(outv[o][0], outv[o][1], outv[o][2], outv[o][3]);
}

// fc1(8->32)+gelu+fc2(32->6), *0.3, + hard core u*nu (ch 0..2). 524,288 threads
__global__ __launch_bounds__(256) void k_out(
    const float* __restrict__ x, const float* __restrict__ u,
    const float* __restrict__ nu,
    const float* __restrict__ fc1w, const float* __restrict__ fc1b,
    const float* __restrict__ fc2w, const float* __restrict__ fc2b,
    float* __restrict__ out)
{
    __shared__ float w1s[256], b1s[32], w2s[192], b2s[6];
    int t = threadIdx.x;
    w1s[t] = fc1w[t];
    if (t < 192) w2s[t] = fc2w[t];
    if (t < 32) b1s[t] = fc1b[t];
    if (t < 6) b2s[t] = fc2b[t];
    __syncthreads();
    int g = blockIdx.x * 256 + t;
    int wq = g & 15, dy = (g >> 4) & 63, dx = (g >> 10) & 63, b = g >> 16;
    size_t sp = (size_t)dx * 4096 + dy * 64 + wq * 4;
    float xin[8][4];
    #pragma unroll
    for (int c = 0; c < 8; ++c) {
        float4 xv = *(const float4*)&x[(size_t)(b * 8 + c) * 262144 + sp];
        xin[c][0] = xv.x; xin[c][1] = xv.y; xin[c][2] = xv.z; xin[c][3] = xv.w;
    }
    float so[6][4];
    #pragma unroll
    for (int c6 = 0; c6 < 6; ++c6)
        #pragma unroll
        for (int j = 0; j < 4; ++j) so[c6][j] = b2s[c6];
    for (int h = 0; h < 32; ++h) {
        float wr[8];
        #pragma unroll
        for (int c = 0; c < 8; ++c) wr[c] = w1s[h * 8 + c];
        const float hb = b1s[h];
        #pragma unroll
        for (int j = 0; j < 4; ++j) {
            float a = hb;
            #pragma unroll
            for (int c = 0; c < 8; ++c) a += xin[c][j] * wr[c];
            float gg = gelu_f(a);
            #pragma unroll
            for (int c6 = 0; c6 < 6; ++c6) so[c6][j] += gg * w2s[c6 * 32 + h];
        }
    }
    const float nuv = nu[0];
    #pragma unroll
    for (int c6 = 0; c6 < 6; ++c6) {
        float4 res;
        float* rp = &res.x;
        if (c6 < 3) {
            float4 uu = *(const float4*)&u[(size_t)(b * 3 + c6) * 262144 + sp];
            const float* up = &uu.x;
            #pragma unroll
            for (int j = 0; j < 4; ++j) rp[j] = 0.3f * so[c6][j] + up[j] * nuv;
        } else {
            #pragma unroll
            for (int j = 0; j < 4; ++j) rp[j] = 0.3f * so[c6][j];
        }
        *(float4*)&out[(size_t)(b * 6 + c6) * 262144 + sp] = res;
    }
}

// pack split re/im spectral leaves into interleaved float2 (n_in==48 path)
__global__ void k_pack(const float* __restrict__ re, const float* __restrict__ im,
                       float2* __restrict__ dst)
{
    int i = blockIdx.x * 256 + threadIdx.x;
    if (i < 4096) dst[i] = make_float2(re[i], im[i]);
}

// ---------------------------------------------------------------------------
extern "C" void kernel_launch(void* const* d_in, const int* in_sizes, int n_in,
                              void* d_out, int out_size, void* d_ws, size_t ws_size,
                              hipStream_t stream)
{
    (void)out_size;
    // ---- size-driven input parsing ----
    const char* leaf[32];
    bool spec_split = false;                 // re/im as separate leaves
    const char* spec_re[16]; const char* spec_im[16];
    int src = 0;
    leaf[0] = (const char*)d_in[src++];      // u
    leaf[1] = (const char*)d_in[src++];      // nu
    leaf[2] = (const char*)d_in[src++];      // fc0_w
    leaf[3] = (const char*)d_in[src++];      // fc0_b
    {
        int s = (src < n_in) ? in_sizes[src] : 4096;
        if (n_in >= 48 && s == 4096) {       // split re/im, adjacent pairs
            spec_split = true;
            for (int i = 0; i < 16; ++i) {
                spec_re[i] = (const char*)d_in[src++];
                spec_im[i] = (const char*)d_in[src++];
            }
        } else {
            int per;
            if (s == 4096 || s == 8192) per = 1;
            else if (s == 16384 || s == 32768) per = 4;
            else per = 16;
            for (int i = 0; i < 16; i += per) {
                const char* base = (const char*)d_in[src++];
                for (int j = 0; j < per; ++j) leaf[4 + i + j] = base + (size_t)j * 4096 * 8;
            }
        }
    }
    {
        int s = (src < n_in) ? in_sizes[src] : 64;
        if (s == 64) { for (int i = 0; i < 4; ++i) leaf[20 + i] = (const char*)d_in[src++]; }
        else { const char* base = (const char*)d_in[src++];
               for (int i = 0; i < 4; ++i) leaf[20 + i] = base + (size_t)i * 64 * 4; }
    }
    {
        int s = (src < n_in) ? in_sizes[src] : 8;
        if (s == 8) { for (int i = 0; i < 4; ++i) leaf[24 + i] = (const char*)d_in[src++]; }
        else { const char* base = (const char*)d_in[src++];
               for (int i = 0; i < 4; ++i) leaf[24 + i] = base + (size_t)i * 8 * 4; }
    }
    leaf[28] = (const char*)d_in[src++];     // fc1_w
    leaf[29] = (const char*)d_in[src++];     // fc1_b
    leaf[30] = (const char*)d_in[src++];     // fc2_w
    leaf[31] = (const char*)d_in[src++];     // fc2_b

    const float* u    = (const float*)leaf[0];
    const float* nu   = (const float*)leaf[1];
    const float* fc0w = (const float*)leaf[2];
    const float* fc0b = (const float*)leaf[3];
    const float* convw[4], *convb[4];
    for (int i = 0; i < 4; ++i) { convw[i] = (const float*)leaf[20 + i];
                                  convb[i] = (const float*)leaf[24 + i]; }
    const float* fc1w = (const float*)leaf[28];
    const float* fc1b = (const float*)leaf[29];
    const float* fc2w = (const float*)leaf[30];
    const float* fc2b = (const float*)leaf[31];

    // ---- scratch layout: x | AQ | BhP | C | O | SP(pack) ----
    const size_t szX = 67108864, szAQ = 8388608, szBP = 1048576,
                 szC = 131072, szO = 131072, szSP = 524288;
    const size_t need = szX + szAQ + szBP + szC + szO + szSP;
    char* ws = (char*)d_ws;
    float* xbuf = (float*)ws;
    char* scr;                               // base for AQ..SP
    if (ws_size >= need) scr = ws + szX;
    else scr = (char*)d_out;                 // dead until k_out writes it
    float2* AQ = (float2*)scr;
    float2* BP = (float2*)(scr + szAQ);
    float2* Cb = (float2*)(scr + szAQ + szBP);
    float2* Ob = (float2*)(scr + szAQ + szBP + szC);
    float2* SP = (float2*)(scr + szAQ + szBP + szC + szO);

    const float2* specw[16];
    if (spec_split) {
        for (int i = 0; i < 16; ++i) {
            hipLaunchKernelGGL(k_pack, dim3(16), dim3(256), 0, stream,
                               (const float*)spec_re[i], (const float*)spec_im[i],
                               SP + (size_t)i * 4096);
            specw[i] = SP + (size_t)i * 4096;
        }
    } else {
        for (int i = 0; i < 16; ++i) specw[i] = (const float2*)leaf[4 + i];
    }
    float* outp = (float*)d_out;

    hipLaunchKernelGGL(k_lift, dim3(8192), dim3(256), 0, stream, u, fc0w, fc0b, xbuf);
    for (int L = 0; L < 4; ++L) {
        hipLaunchKernelGGL(k_fwdW, dim3(1024), dim3(256), 0, stream, xbuf, AQ);
        hipLaunchKernelGGL(k_fwdH, dim3(128), dim3(256), 0, stream, AQ, BP);
        hipLaunchKernelGGL(k_fwdD, dim3(16), dim3(256), 0, stream, BP, Cb);
        hipLaunchKernelGGL(k_mix, dim3(64), dim3(256), 0, stream,
                           Cb, specw[L*4+0], specw[L*4+1], specw[L*4+2], specw[L*4+3], Ob);
        hipLaunchKernelGGL(k_invD, dim3(128), dim3(256), 0, stream, Ob, BP);
        hipLaunchKernelGGL(k_invH, dim3(1024), dim3(256), 0, stream, BP, AQ);
        hipLaunchKernelGGL(k_pt, dim3(2048), dim3(256), 0, stream,
                           xbuf, AQ, convw[L], convb[L], (L < 3) ? 1 : 0);
    }
    hipLaunchKernelGGL(k_out, dim3(2048), dim3(256), 0, stream,
                       xbuf, u, nu, fc1w, fc1b, fc2w, fc2b, outp);
}

// Round 4
// 424.412 us; speedup vs baseline: 1.2628x; 1.2628x over previous
//
#include <hip/hip_runtime.h>

// FNO3d forward, MI355X. Round 4: fused pipeline rebuilt from the verified
// R3 stage math (R2's failure was an A-stride bug: 65536 vs 16384 — fixed).
//
// Layouts:
//   x : float [B=8][C=8][64][64][64]          (67,108,864 B)
//   A : float2[8][8][dx=64][dy=64][kz=4]      ( 8,388,608 B)  per-(b,c) stride 16384
//   C : float2[8][8][kx=8][ky=8][kz=4]        (   131,072 B)
//   O : float2[8][8][kx=8][ky=8][kz=4]        (   131,072 B)
// Pipeline: k_liftA; per layer: k_head (A->C), k_mix (C->O),
//           k_ptA (O->Ps->Qs in LDS, irfftW + conv + gelu, x in place, new A)
//           or k_ptout (layer 3: same front, then fc1+gelu+fc2 + hard core).

#define TWO_PI_OVER_64 0.09817477042468103

__device__ __forceinline__ float gelu_fast(float x) {
    float z = 0.7978845608028654f * (x + 0.044715f * x * x * x);
    float e = __expf(2.0f * z);
    float th = 1.0f - 2.0f / (e + 1.0f);   // tanh(z); saturates correctly at +-inf
    return 0.5f * x * (1.0f + th);
}

#define BUILD_TW() \
    __shared__ float twc[64], tws[64]; \
    if (threadIdx.x < 64) { \
        double a_ = TWO_PI_OVER_64 * (double)threadIdx.x; \
        twc[threadIdx.x] = (float)cos(a_); tws[threadIdx.x] = (float)sin(a_); \
    }

// ---------------------------------------------------------------------------
// Lift (3->8 ch) + forward W-DFT. grid 2048 = b(8)*dx(64)*dyq(4); block 256.
// Thread: dyl = t>>4 (16 rows), wq = t&15 (4 w each).
// ---------------------------------------------------------------------------
__global__ __launch_bounds__(256) void k_liftA(
    const float* __restrict__ u, const float* __restrict__ fc0w,
    const float* __restrict__ fc0b, float* __restrict__ x,
    float2* __restrict__ A)
{
    BUILD_TW();
    __shared__ float vbuf[8 * 16 * 65];
    const int t = threadIdx.x, bid = blockIdx.x;
    const int b = bid >> 8, dx = (bid >> 2) & 63, dy0 = (bid & 3) * 16;
    const int dyl = t >> 4, wq = t & 15;
    const size_t sp = (size_t)dx * 4096 + (size_t)(dy0 + dyl) * 64 + wq * 4;
    float uin[3][4];
    #pragma unroll
    for (int c = 0; c < 3; ++c) {
        float4 v = *(const float4*)&u[(size_t)(b * 3 + c) * 262144 + sp];
        uin[c][0] = v.x; uin[c][1] = v.y; uin[c][2] = v.z; uin[c][3] = v.w;
    }
    #pragma unroll
    for (int o = 0; o < 8; ++o) {
        float w0 = fc0w[o * 3 + 0], w1 = fc0w[o * 3 + 1], w2 = fc0w[o * 3 + 2];
        float bb = fc0b[o];
        float v[4];
        #pragma unroll
        for (int j = 0; j < 4; ++j)
            v[j] = bb + uin[0][j] * w0 + uin[1][j] * w1 + uin[2][j] * w2;
        *(float4*)&x[(size_t)(b * 8 + o) * 262144 + sp] = make_float4(v[0], v[1], v[2], v[3]);
        #pragma unroll
        for (int j = 0; j < 4; ++j) vbuf[(o * 16 + dyl) * 65 + wq * 4 + j] = v[j];
    }
    __syncthreads();
    if (t < 128) {
        int o = t >> 4, dyl2 = t & 15;
        float ar[4] = {0.f,0.f,0.f,0.f}, ai[4] = {0.f,0.f,0.f,0.f};
        for (int w = 0; w < 64; ++w) {
            float v = vbuf[(o * 16 + dyl2) * 65 + w];
            #pragma unroll
            for (int k = 0; k < 4; ++k) {
                int ti = (k * w) & 63;
                ar[k] += v * twc[ti]; ai[k] -= v * tws[ti];
            }
        }
        float2* Ao = A + ((size_t)(b * 8 + o) * 4096 + dx * 64 + dy0 + dyl2) * 4;
        #pragma unroll
        for (int k = 0; k < 4; ++k) Ao[k] = make_float2(ar[k], ai[k]);
    }
}

// ---------------------------------------------------------------------------
// Forward H then D DFT: A[b,c,dx,dy,kz] -> C[b,c,kx,ky,kz]. grid 64 = b*8+c.
// (R2 structure with the stride bug fixed: per-(b,c) A stride = 16384.)
// ---------------------------------------------------------------------------
__global__ __launch_bounds__(256) void k_head(const float2* __restrict__ A,
                                              float2* __restrict__ C)
{
    BUILD_TW();
    __shared__ float2 Bt[64 * 8 * 4];  // [dx][kyi][kz]
    const int t = threadIdx.x, bid = blockIdx.x;
    const int b = bid >> 3, c = bid & 7;
    __syncthreads();
    const float2* Ab = A + (size_t)(b * 8 + c) * 16384;
    for (int it = t; it < 2048; it += 256) {
        int kz = it & 3, kyi = (it >> 2) & 7, dx = it >> 5;
        int kyv = kyi < 4 ? kyi : kyi + 56;
        float re = 0.f, im = 0.f;
        const float2* row = Ab + dx * 256 + kz;
        for (int dy = 0; dy < 64; ++dy) {
            float2 a = row[dy * 4];
            int ti = (kyv * dy) & 63;
            float cc = twc[ti], ss = tws[ti];
            re += a.x * cc + a.y * ss;   // * e^{-i phi}
            im += a.y * cc - a.x * ss;
        }
        Bt[it] = make_float2(re, im);    // it == (dx*8+kyi)*4+kz
    }
    __syncthreads();
    {
        int kz = t & 3, kyi = (t >> 2) & 7, kxi = t >> 5;
        int kxv = kxi < 4 ? kxi : kxi + 56;
        float re = 0.f, im = 0.f;
        for (int dxx = 0; dxx < 64; ++dxx) {
            float2 a = Bt[(dxx * 8 + kyi) * 4 + kz];
            int ti = (kxv * dxx) & 63;
            float cc = twc[ti], ss = tws[ti];
            re += a.x * cc + a.y * ss;
            im += a.y * cc - a.x * ss;
        }
        C[(size_t)(b * 8 + c) * 256 + t] = make_float2(re, im);
    }
}

// ---------------------------------------------------------------------------
// Spectral channel mix (verbatim R3). grid 64, block 256.
// ---------------------------------------------------------------------------
__global__ __launch_bounds__(256) void k_mix(
    const float2* __restrict__ C,
    const float2* __restrict__ w1, const float2* __restrict__ w2,
    const float2* __restrict__ w3, const float2* __restrict__ w4,
    float2* __restrict__ O)
{
    int gid = blockIdx.x * 256 + threadIdx.x;
    int kz = gid & 3, ky = (gid >> 2) & 7, kx = (gid >> 5) & 7;
    int o = (gid >> 8) & 7, b = gid >> 11;
    const float2* wsel = (kx < 4) ? ((ky < 4) ? w1 : w3) : ((ky < 4) ? w2 : w4);
    int kxw = kx & 3, kyw = ky & 3;
    float re = 0.f, im = 0.f;
    for (int i = 0; i < 8; ++i) {
        float2 cv = C[(((size_t)(b * 8 + i) * 8 + kx) * 8 + ky) * 4 + kz];
        float2 wv = wsel[(((size_t)(i * 8 + o) * 4 + kxw) * 4 + kyw) * 4 + kz];
        re += cv.x * wv.x - cv.y * wv.y;
        im += cv.x * wv.y + cv.y * wv.x;
    }
    O[gid] = make_float2(re, im);
}

// ---------------------------------------------------------------------------
// Inverse D/H DFT in LDS + irfftW + conv + gelu + x in place + next-layer A.
// grid 2048 = b(8)*dx(64)*dyq(4); block 256 (dyl = t>>4, wq = t&15).
// ---------------------------------------------------------------------------
__global__ __launch_bounds__(256) void k_ptA(
    float* __restrict__ x, const float2* __restrict__ O,
    const float* __restrict__ cw, const float* __restrict__ cb,
    float2* __restrict__ A)
{
    BUILD_TW();
    __shared__ float2 Ps[8 * 8 * 4];    // [o][ky][kz]
    __shared__ float2 Qs[8 * 16 * 4];   // [o][dyl][kz]
    __shared__ float vbuf[8 * 16 * 65];
    const int t = threadIdx.x, bid = blockIdx.x;
    const int b = bid >> 8, dx = (bid >> 2) & 63, dy0 = (bid & 3) * 16;
    __syncthreads();
    {   // Ps: verbatim R3 k_invD inner loop (O from global, L2-hot 131 KB)
        int kz = t & 3, ky = (t >> 2) & 7, o = t >> 5;
        float re = 0.f, im = 0.f;
        #pragma unroll
        for (int kxi = 0; kxi < 8; ++kxi) {
            int kxv = kxi < 4 ? kxi : kxi + 56;
            int ti = (kxv * dx) & 63;
            float2 v = O[(((size_t)(b * 8 + o) * 8 + kxi) * 8 + ky) * 4 + kz];
            float cc = twc[ti], ss = tws[ti];
            re += v.x * cc - v.y * ss;   // * e^{+i phi}
            im += v.y * cc + v.x * ss;
        }
        Ps[t] = make_float2(re, im);     // t == (o*8+ky)*4+kz
    }
    __syncthreads();
    for (int it = t; it < 512; it += 256) {  // Qs: verbatim R3 k_invH inner
        int kz = it & 3, dyl = (it >> 2) & 15, o = it >> 6;
        int dy = dy0 + dyl;
        float re = 0.f, im = 0.f;
        #pragma unroll
        for (int kyi = 0; kyi < 8; ++kyi) {
            int kyv = kyi < 4 ? kyi : kyi + 56;
            int ti = (kyv * dy) & 63;
            float2 v = Ps[(o * 8 + kyi) * 4 + kz];
            float cc = twc[ti], ss = tws[ti];
            re += v.x * cc - v.y * ss;
            im += v.y * cc + v.x * ss;
        }
        Qs[(o * 16 + dyl) * 4 + kz] = make_float2(re, im);
    }
    __syncthreads();
    const int dyl = t >> 4, wq = t & 15;
    const size_t sp = (size_t)dx * 4096 + (size_t)(dy0 + dyl) * 64 + wq * 4;
    float c1[4], s1[4], c2[4], s2[4], c3[4], s3[4];
    #pragma unroll
    for (int j = 0; j < 4; ++j) {
        int w = wq * 4 + j;
        c1[j] = twc[w];             s1[j] = tws[w];
        c2[j] = twc[(2 * w) & 63];  s2[j] = tws[(2 * w) & 63];
        c3[j] = twc[(3 * w) & 63];  s3[j] = tws[(3 * w) & 63];
    }
    float xin[8][4];
    #pragma unroll
    for (int c = 0; c < 8; ++c) {
        float4 v = *(const float4*)&x[(size_t)(b * 8 + c) * 262144 + sp];
        xin[c][0] = v.x; xin[c][1] = v.y; xin[c][2] = v.z; xin[c][3] = v.w;
    }
    const float invN3 = 1.0f / 262144.0f;
    #pragma unroll
    for (int o = 0; o < 8; ++o) {
        float2 q0 = Qs[(o*16+dyl)*4+0], q1 = Qs[(o*16+dyl)*4+1];
        float2 q2 = Qs[(o*16+dyl)*4+2], q3 = Qs[(o*16+dyl)*4+3];
        float outj[4];
        #pragma unroll
        for (int j = 0; j < 4; ++j) {
            float x1 = q0.x + 2.f * (q1.x * c1[j] - q1.y * s1[j]
                                   + q2.x * c2[j] - q2.y * s2[j]
                                   + q3.x * c3[j] - q3.y * s3[j]);
            x1 *= invN3;
            float x2 = cb[o];
            #pragma unroll
            for (int c = 0; c < 8; ++c) x2 += cw[o * 8 + c] * xin[c][j];
            outj[j] = gelu_fast(x1 + x2);
        }
        *(float4*)&x[(size_t)(b * 8 + o) * 262144 + sp] =
            make_float4(outj[0], outj[1], outj[2], outj[3]);
        #pragma unroll
        for (int j = 0; j < 4; ++j) vbuf[(o * 16 + dyl) * 65 + wq * 4 + j] = outj[j];
    }
    __syncthreads();
    if (t < 128) {   // forward W-DFT of the new x (verbatim R3 k_fwdW on LDS)
        int o = t >> 4, dyl2 = t & 15;
        float ar[4] = {0.f,0.f,0.f,0.f}, ai[4] = {0.f,0.f,0.f,0.f};
        for (int w = 0; w < 64; ++w) {
            float v = vbuf[(o * 16 + dyl2) * 65 + w];
            #pragma unroll
            for (int k = 0; k < 4; ++k) {
                int ti = (k * w) & 63;
                ar[k] += v * twc[ti]; ai[k] -= v * tws[ti];
            }
        }
        float2* Ao = A + ((size_t)(b * 8 + o) * 4096 + dx * 64 + dy0 + dyl2) * 4;
        #pragma unroll
        for (int k = 0; k < 4; ++k) Ao[k] = make_float2(ar[k], ai[k]);
    }
}

// ---------------------------------------------------------------------------
// Layer 3: inverse DFT + conv (no gelu) -> fc1+gelu+fc2, + hard core u*nu.
// Writes d_out only. grid 2048, block 256.
// ---------------------------------------------------------------------------
__global__ __launch_bounds__(256) void k_ptout(
    const float* __restrict__ x, const float2* __restrict__ O,
    const float* __restrict__ cw, const float* __restrict__ cb,
    const float* __restrict__ u, const float* __restrict__ nu,
    const float* __restrict__ fc1w, const float* __restrict__ fc1b,
    const float* __restrict__ fc2w, const float* __restrict__ fc2b,
    float* __restrict__ out)
{
    BUILD_TW();
    __shared__ float2 Ps[8 * 8 * 4];
    __shared__ float2 Qs[8 * 16 * 4];
    __shared__ float w1s[256], b1s[32], w2s[192], b2s[6];
    const int t = threadIdx.x, bid = blockIdx.x;
    const int b = bid >> 8, dx = (bid >> 2) & 63, dy0 = (bid & 3) * 16;
    w1s[t] = fc1w[t];
    if (t < 192) w2s[t] = fc2w[t];
    if (t < 32) b1s[t] = fc1b[t];
    if (t < 6) b2s[t] = fc2b[t];
    __syncthreads();
    {
        int kz = t & 3, ky = (t >> 2) & 7, o = t >> 5;
        float re = 0.f, im = 0.f;
        #pragma unroll
        for (int kxi = 0; kxi < 8; ++kxi) {
            int kxv = kxi < 4 ? kxi : kxi + 56;
            int ti = (kxv * dx) & 63;
            float2 v = O[(((size_t)(b * 8 + o) * 8 + kxi) * 8 + ky) * 4 + kz];
            float cc = twc[ti], ss = tws[ti];
            re += v.x * cc - v.y * ss;
            im += v.y * cc + v.x * ss;
        }
        Ps[t] = make_float2(re, im);
    }
    __syncthreads();
    for (int it = t; it < 512; it += 256) {
        int kz = it & 3, dyl = (it >> 2) & 15, o = it >> 6;
        int dy = dy0 + dyl;
        float re = 0.f, im = 0.f;
        #pragma unroll
        for (int kyi = 0; kyi < 8; ++kyi) {
            int kyv = kyi < 4 ? kyi : kyi + 56;
            int ti = (kyv * dy) & 63;
            float2 v = Ps[(o * 8 + kyi) * 4 + kz];
            float cc = twc[ti], ss = tws[ti];
            re += v.x * cc - v.y * ss;
            im += v.y * cc + v.x * ss;
        }
        Qs[(o * 16 + dyl) * 4 + kz] = make_float2(re, im);
    }
    __syncthreads();
    const int dyl = t >> 4, wq = t & 15;
    const size_t sp = (size_t)dx * 4096 + (size_t)(dy0 + dyl) * 64 + wq * 4;
    float c1[4], s1[4], c2[4], s2[4], c3[4], s3[4];
    #pragma unroll
    for (int j = 0; j < 4; ++j) {
        int w = wq * 4 + j;
        c1[j] = twc[w];             s1[j] = tws[w];
        c2[j] = twc[(2 * w) & 63];  s2[j] = tws[(2 * w) & 63];
        c3[j] = twc[(3 * w) & 63];  s3[j] = tws[(3 * w) & 63];
    }
    float xin[8][4];
    #pragma unroll
    for (int c = 0; c < 8; ++c) {
        float4 v = *(const float4*)&x[(size_t)(b * 8 + c) * 262144 + sp];
        xin[c][0] = v.x; xin[c][1] = v.y; xin[c][2] = v.z; xin[c][3] = v.w;
    }
    const float invN3 = 1.0f / 262144.0f;
    float vv[8][4];   // layer-3 activations (no gelu)
    #pragma unroll
    for (int o = 0; o < 8; ++o) {
        float2 q0 = Qs[(o*16+dyl)*4+0], q1 = Qs[(o*16+dyl)*4+1];
        float2 q2 = Qs[(o*16+dyl)*4+2], q3 = Qs[(o*16+dyl)*4+3];
        #pragma unroll
        for (int j = 0; j < 4; ++j) {
            float x1 = q0.x + 2.f * (q1.x * c1[j] - q1.y * s1[j]
                                   + q2.x * c2[j] - q2.y * s2[j]
                                   + q3.x * c3[j] - q3.y * s3[j]);
            x1 *= invN3;
            float x2 = cb[o];
            #pragma unroll
            for (int c = 0; c < 8; ++c) x2 += cw[o * 8 + c] * xin[c][j];
            vv[o][j] = x1 + x2;
        }
    }
    float so[6][4];
    #pragma unroll
    for (int c6 = 0; c6 < 6; ++c6)
        #pragma unroll
        for (int j = 0; j < 4; ++j) so[c6][j] = b2s[c6];
    for (int h = 0; h < 32; ++h) {
        float wr[8];
        #pragma unroll
        for (int c = 0; c < 8; ++c) wr[c] = w1s[h * 8 + c];
        const float hb = b1s[h];
        #pragma unroll
        for (int j = 0; j < 4; ++j) {
            float a = hb;
            #pragma unroll
            for (int c = 0; c < 8; ++c) a += vv[c][j] * wr[c];
            float g = gelu_fast(a);
            #pragma unroll
            for (int c6 = 0; c6 < 6; ++c6) so[c6][j] += g * w2s[c6 * 32 + h];
        }
    }
    const float nuv = nu[0];
    #pragma unroll
    for (int c6 = 0; c6 < 6; ++c6) {
        float4 res;
        float* rp = &res.x;
        if (c6 < 3) {
            float4 uu = *(const float4*)&u[(size_t)(b * 3 + c6) * 262144 + sp];
            const float* up = &uu.x;
            #pragma unroll
            for (int j = 0; j < 4; ++j) rp[j] = 0.3f * so[c6][j] + up[j] * nuv;
        } else {
            #pragma unroll
            for (int j = 0; j < 4; ++j) rp[j] = 0.3f * so[c6][j];
        }
        *(float4*)&out[(size_t)(b * 6 + c6) * 262144 + sp] = res;
    }
}

// pack split re/im spectral leaves into interleaved float2 (n_in==48 path)
__global__ void k_pack(const float* __restrict__ re, const float* __restrict__ im,
                       float2* __restrict__ dst)
{
    int i = blockIdx.x * 256 + threadIdx.x;
    if (i < 4096) dst[i] = make_float2(re[i], im[i]);
}

// ---------------------------------------------------------------------------
extern "C" void kernel_launch(void* const* d_in, const int* in_sizes, int n_in,
                              void* d_out, int out_size, void* d_ws, size_t ws_size,
                              hipStream_t stream)
{
    (void)out_size;
    // ---- size-driven input parsing (verbatim R3) ----
    const char* leaf[32];
    bool spec_split = false;
    const char* spec_re[16]; const char* spec_im[16];
    int src = 0;
    leaf[0] = (const char*)d_in[src++];
    leaf[1] = (const char*)d_in[src++];
    leaf[2] = (const char*)d_in[src++];
    leaf[3] = (const char*)d_in[src++];
    {
        int s = (src < n_in) ? in_sizes[src] : 4096;
        if (n_in >= 48 && s == 4096) {
            spec_split = true;
            for (int i = 0; i < 16; ++i) {
                spec_re[i] = (const char*)d_in[src++];
                spec_im[i] = (const char*)d_in[src++];
            }
        } else {
            int per;
            if (s == 4096 || s == 8192) per = 1;
            else if (s == 16384 || s == 32768) per = 4;
            else per = 16;
            for (int i = 0; i < 16; i += per) {
                const char* base = (const char*)d_in[src++];
                for (int j = 0; j < per; ++j) leaf[4 + i + j] = base + (size_t)j * 4096 * 8;
            }
        }
    }
    {
        int s = (src < n_in) ? in_sizes[src] : 64;
        if (s == 64) { for (int i = 0; i < 4; ++i) leaf[20 + i] = (const char*)d_in[src++]; }
        else { const char* base = (const char*)d_in[src++];
               for (int i = 0; i < 4; ++i) leaf[20 + i] = base + (size_t)i * 64 * 4; }
    }
    {
        int s = (src < n_in) ? in_sizes[src] : 8;
        if (s == 8) { for (int i = 0; i < 4; ++i) leaf[24 + i] = (const char*)d_in[src++]; }
        else { const char* base = (const char*)d_in[src++];
               for (int i = 0; i < 4; ++i) leaf[24 + i] = base + (size_t)i * 8 * 4; }
    }
    leaf[28] = (const char*)d_in[src++];
    leaf[29] = (const char*)d_in[src++];
    leaf[30] = (const char*)d_in[src++];
    leaf[31] = (const char*)d_in[src++];

    const float* u    = (const float*)leaf[0];
    const float* nu   = (const float*)leaf[1];
    const float* fc0w = (const float*)leaf[2];
    const float* fc0b = (const float*)leaf[3];
    const float* convw[4], *convb[4];
    for (int i = 0; i < 4; ++i) { convw[i] = (const float*)leaf[20 + i];
                                  convb[i] = (const float*)leaf[24 + i]; }
    const float* fc1w = (const float*)leaf[28];
    const float* fc1b = (const float*)leaf[29];
    const float* fc2w = (const float*)leaf[30];
    const float* fc2b = (const float*)leaf[31];

    // ---- scratch: x | A | C | O | SP.  Fallback: A,C,SP in d_out (dead
    // before k_ptout); O must stay in ws (live during k_ptout). ----
    const size_t szX = 67108864, szA = 8388608, szC = 131072,
                 szO = 131072, szSP = 524288;
    char* ws = (char*)d_ws;
    float* xbuf = (float*)ws;
    float2 *Abuf, *Cbuf, *Obuf, *SP;
    if (ws_size >= szX + szA + szC + szO + szSP) {
        Abuf = (float2*)(ws + szX);
        Cbuf = (float2*)(ws + szX + szA);
        Obuf = (float2*)(ws + szX + szA + szC);
        SP   = (float2*)(ws + szX + szA + szC + szO);
    } else {
        Obuf = (float2*)(ws + szX);
        Abuf = (float2*)d_out;
        Cbuf = (float2*)((char*)d_out + szA);
        SP   = (float2*)((char*)d_out + szA + szC);
    }

    const float2* specw[16];
    if (spec_split) {
        for (int i = 0; i < 16; ++i) {
            hipLaunchKernelGGL(k_pack, dim3(16), dim3(256), 0, stream,
                               (const float*)spec_re[i], (const float*)spec_im[i],
                               SP + (size_t)i * 4096);
            specw[i] = SP + (size_t)i * 4096;
        }
    } else {
        for (int i = 0; i < 16; ++i) specw[i] = (const float2*)leaf[4 + i];
    }
    float* outp = (float*)d_out;

    hipLaunchKernelGGL(k_liftA, dim3(2048), dim3(256), 0, stream, u, fc0w, fc0b, xbuf, Abuf);
    for (int L = 0; L < 4; ++L) {
        hipLaunchKernelGGL(k_head, dim3(64), dim3(256), 0, stream, Abuf, Cbuf);
        hipLaunchKernelGGL(k_mix, dim3(64), dim3(256), 0, stream,
                           Cbuf, specw[L*4+0], specw[L*4+1], specw[L*4+2], specw[L*4+3], Obuf);
        if (L < 3) {
            hipLaunchKernelGGL(k_ptA, dim3(2048), dim3(256), 0, stream,
                               xbuf, Obuf, convw[L], convb[L], Abuf);
        } else {
            hipLaunchKernelGGL(k_ptout, dim3(2048), dim3(256), 0, stream,
                               xbuf, Obuf, convw[3], convb[3], u, nu,
                               fc1w, fc1b, fc2w, fc2b, outp);
        }
    }
}

// Round 5
// 386.313 us; speedup vs baseline: 1.3873x; 1.0986x over previous
//
#include <hip/hip_runtime.h>

// FNO3d forward, MI355X. Round 5: same R4 fused structure;
//  - fc weights read via wave-uniform global loads (SGPR) instead of LDS
//  - gelu via sigmoid form (exp2 + rcp), same tanh-approx math
//  - k_ptA/k_liftA: two-pass vbuf (half channels) -> LDS 40->23 KB,
//    A-DFT tail distributed over all 256 threads
//  - Qs fragments read as float4 (ds_read_b128)
//
// Layouts:
//   x : float [B=8][C=8][64][64][64]          (67,108,864 B)
//   A : float2[8][8][dx=64][dy=64][kz=4]      ( 8,388,608 B)  per-(b,c) stride 16384
//   C : float2[8][8][kx=8][ky=8][kz=4]        (   131,072 B)
//   O : float2[8][8][kx=8][ky=8][kz=4]        (   131,072 B)

#define TWO_PI_OVER_64 0.09817477042468103

__device__ __forceinline__ float gelu_fast(float x) {
    // tanh-approx gelu: x * sigmoid(1.5957691*(x + 0.044715 x^3))
    //                 = x * rcp(1 + exp2(-2.3022083 * (x + 0.044715 x^3)))
    float x2 = x * x;
    float p  = x * (1.0f + 0.044715f * x2);
    float e  = __builtin_amdgcn_exp2f(-2.3022083f * p);
    return x * __builtin_amdgcn_rcpf(1.0f + e);
}

#define BUILD_TW() \
    __shared__ float twc[64], tws[64]; \
    if (threadIdx.x < 64) { \
        double a_ = TWO_PI_OVER_64 * (double)threadIdx.x; \
        twc[threadIdx.x] = (float)cos(a_); tws[threadIdx.x] = (float)sin(a_); \
    }

// ---------------------------------------------------------------------------
// Lift (3->8 ch) + forward W-DFT, two-pass vbuf.
// grid 2048 = b(8)*dx(64)*dyq(4); block 256 (dyl = t>>4, wq = t&15).
// ---------------------------------------------------------------------------
__global__ __launch_bounds__(256) void k_liftA(
    const float* __restrict__ u, const float* __restrict__ fc0w,
    const float* __restrict__ fc0b, float* __restrict__ x,
    float2* __restrict__ A)
{
    BUILD_TW();
    __shared__ float vbuf[4 * 16 * 65];     // half the channels at a time
    const int t = threadIdx.x, bid = blockIdx.x;
    const int b = bid >> 8, dx = (bid >> 2) & 63, dy0 = (bid & 3) * 16;
    const int dyl = t >> 4, wq = t & 15;
    const size_t sp = (size_t)dx * 4096 + (size_t)(dy0 + dyl) * 64 + wq * 4;
    float uin[3][4];
    #pragma unroll
    for (int c = 0; c < 3; ++c) {
        float4 v = *(const float4*)&u[(size_t)(b * 3 + c) * 262144 + sp];
        uin[c][0] = v.x; uin[c][1] = v.y; uin[c][2] = v.z; uin[c][3] = v.w;
    }
    const int to = t >> 6, tdyl = (t >> 2) & 15, tkz = t & 3;  // tail mapping
    for (int half = 0; half < 2; ++half) {
        __syncthreads();   // tw ready (half 0) / vbuf free (half 1)
        #pragma unroll
        for (int oo = 0; oo < 4; ++oo) {
            int o = half * 4 + oo;
            float w0 = fc0w[o * 3 + 0], w1 = fc0w[o * 3 + 1], w2 = fc0w[o * 3 + 2];
            float bb = fc0b[o];
            float v[4];
            #pragma unroll
            for (int j = 0; j < 4; ++j)
                v[j] = bb + uin[0][j] * w0 + uin[1][j] * w1 + uin[2][j] * w2;
            *(float4*)&x[(size_t)(b * 8 + o) * 262144 + sp] =
                make_float4(v[0], v[1], v[2], v[3]);
            #pragma unroll
            for (int j = 0; j < 4; ++j) vbuf[(oo * 16 + dyl) * 65 + wq * 4 + j] = v[j];
        }
        __syncthreads();
        // W-DFT tail: one (o,dy,kz) per thread, rotor index (no multiplies)
        float ar = 0.f, ai = 0.f; int ti = 0;
        const float* vr = &vbuf[(to * 16 + tdyl) * 65];
        for (int w = 0; w < 64; ++w) {
            float v = vr[w];
            ar += v * twc[ti]; ai -= v * tws[ti];
            ti = (ti + tkz) & 63;
        }
        A[((size_t)(b * 8 + half * 4 + to) * 4096 + dx * 64 + dy0 + tdyl) * 4 + tkz] =
            make_float2(ar, ai);
    }
}

// ---------------------------------------------------------------------------
// Forward H then D DFT: A[b,c,dx,dy,kz] -> C[b,c,kx,ky,kz]. grid 64 = b*8+c.
// ---------------------------------------------------------------------------
__global__ __launch_bounds__(256) void k_head(const float2* __restrict__ A,
                                              float2* __restrict__ C)
{
    BUILD_TW();
    __shared__ float2 Bt[64 * 8 * 4];  // [dx][kyi][kz]
    const int t = threadIdx.x, bid = blockIdx.x;
    const int b = bid >> 3, c = bid & 7;
    __syncthreads();
    const float2* Ab = A + (size_t)(b * 8 + c) * 16384;
    for (int it = t; it < 2048; it += 256) {
        int kz = it & 3, kyi = (it >> 2) & 7, dx = it >> 5;
        int kyv = kyi < 4 ? kyi : kyi + 56;
        float re = 0.f, im = 0.f;
        const float2* row = Ab + dx * 256 + kz;
        for (int dy = 0; dy < 64; ++dy) {
            float2 a = row[dy * 4];
            int ti = (kyv * dy) & 63;
            float cc = twc[ti], ss = tws[ti];
            re += a.x * cc + a.y * ss;   // * e^{-i phi}
            im += a.y * cc - a.x * ss;
        }
        Bt[it] = make_float2(re, im);    // it == (dx*8+kyi)*4+kz
    }
    __syncthreads();
    {
        int kz = t & 3, kyi = (t >> 2) & 7, kxi = t >> 5;
        int kxv = kxi < 4 ? kxi : kxi + 56;
        float re = 0.f, im = 0.f;
        for (int dxx = 0; dxx < 64; ++dxx) {
            float2 a = Bt[(dxx * 8 + kyi) * 4 + kz];
            int ti = (kxv * dxx) & 63;
            float cc = twc[ti], ss = tws[ti];
            re += a.x * cc + a.y * ss;
            im += a.y * cc - a.x * ss;
        }
        C[(size_t)(b * 8 + c) * 256 + t] = make_float2(re, im);
    }
}

// ---------------------------------------------------------------------------
// Spectral channel mix. grid 64, block 256.
// ---------------------------------------------------------------------------
__global__ __launch_bounds__(256) void k_mix(
    const float2* __restrict__ C,
    const float2* __restrict__ w1, const float2* __restrict__ w2,
    const float2* __restrict__ w3, const float2* __restrict__ w4,
    float2* __restrict__ O)
{
    int gid = blockIdx.x * 256 + threadIdx.x;
    int kz = gid & 3, ky = (gid >> 2) & 7, kx = (gid >> 5) & 7;
    int o = (gid >> 8) & 7, b = gid >> 11;
    const float2* wsel = (kx < 4) ? ((ky < 4) ? w1 : w3) : ((ky < 4) ? w2 : w4);
    int kxw = kx & 3, kyw = ky & 3;
    float re = 0.f, im = 0.f;
    for (int i = 0; i < 8; ++i) {
        float2 cv = C[(((size_t)(b * 8 + i) * 8 + kx) * 8 + ky) * 4 + kz];
        float2 wv = wsel[(((size_t)(i * 8 + o) * 4 + kxw) * 4 + kyw) * 4 + kz];
        re += cv.x * wv.x - cv.y * wv.y;
        im += cv.x * wv.y + cv.y * wv.x;
    }
    O[gid] = make_float2(re, im);
}

// ---------------------------------------------------------------------------
// Inverse D/H DFT in LDS + irfftW + conv + gelu + x in place + next-layer A.
// Two-pass vbuf; tail distributed over all 256 threads.
// grid 2048 = b(8)*dx(64)*dyq(4); block 256 (dyl = t>>4, wq = t&15).
// ---------------------------------------------------------------------------
__global__ __launch_bounds__(256) void k_ptA(
    float* __restrict__ x, const float2* __restrict__ O,
    const float* __restrict__ cw, const float* __restrict__ cb,
    float2* __restrict__ A)
{
    BUILD_TW();
    __shared__ float2 Ps[256];          // [o][ky][kz]
    __shared__ float2 Qs[8 * 16 * 4];   // [o][dyl][kz]
    __shared__ float vbuf[4 * 16 * 65]; // half channels
    const int t = threadIdx.x, bid = blockIdx.x;
    const int b = bid >> 8, dx = (bid >> 2) & 63, dy0 = (bid & 3) * 16;
    __syncthreads();
    {   // Ps
        int kz = t & 3, ky = (t >> 2) & 7, o = t >> 5;
        float re = 0.f, im = 0.f;
        #pragma unroll
        for (int kxi = 0; kxi < 8; ++kxi) {
            int kxv = kxi < 4 ? kxi : kxi + 56;
            int ti = (kxv * dx) & 63;
            float2 v = O[(((size_t)(b * 8 + o) * 8 + kxi) * 8 + ky) * 4 + kz];
            float cc = twc[ti], ss = tws[ti];
            re += v.x * cc - v.y * ss;   // * e^{+i phi}
            im += v.y * cc + v.x * ss;
        }
        Ps[t] = make_float2(re, im);
    }
    __syncthreads();
    for (int it = t; it < 512; it += 256) {  // Qs
        int kz = it & 3, dyl = (it >> 2) & 15, o = it >> 6;
        int dy = dy0 + dyl;
        float re = 0.f, im = 0.f;
        #pragma unroll
        for (int kyi = 0; kyi < 8; ++kyi) {
            int kyv = kyi < 4 ? kyi : kyi + 56;
            int ti = (kyv * dy) & 63;
            float2 v = Ps[(o * 8 + kyi) * 4 + kz];
            float cc = twc[ti], ss = tws[ti];
            re += v.x * cc - v.y * ss;
            im += v.y * cc + v.x * ss;
        }
        Qs[(o * 16 + dyl) * 4 + kz] = make_float2(re, im);
    }
    __syncthreads();
    const int dyl = t >> 4, wq = t & 15;
    const size_t sp = (size_t)dx * 4096 + (size_t)(dy0 + dyl) * 64 + wq * 4;
    float c1[4], s1[4], c2[4], s2[4], c3[4], s3[4];
    #pragma unroll
    for (int j = 0; j < 4; ++j) {
        int w = wq * 4 + j;
        c1[j] = twc[w];             s1[j] = tws[w];
        c2[j] = twc[(2 * w) & 63];  s2[j] = tws[(2 * w) & 63];
        c3[j] = twc[(3 * w) & 63];  s3[j] = tws[(3 * w) & 63];
    }
    float xin[8][4];
    #pragma unroll
    for (int c = 0; c < 8; ++c) {
        float4 v = *(const float4*)&x[(size_t)(b * 8 + c) * 262144 + sp];
        xin[c][0] = v.x; xin[c][1] = v.y; xin[c][2] = v.z; xin[c][3] = v.w;
    }
    const float invN3 = 1.0f / 262144.0f;
    float valhi[4][4];
    #pragma unroll
    for (int o = 0; o < 8; ++o) {
        float4 qa = *(const float4*)&Qs[(o * 16 + dyl) * 4];      // q0,q1
        float4 qb = *(const float4*)&Qs[(o * 16 + dyl) * 4 + 2];  // q2,q3
        float outj[4];
        #pragma unroll
        for (int j = 0; j < 4; ++j) {
            float x1 = qa.x + 2.f * (qa.z * c1[j] - qa.w * s1[j]
                                   + qb.x * c2[j] - qb.y * s2[j]
                                   + qb.z * c3[j] - qb.w * s3[j]);
            x1 *= invN3;
            float x2 = cb[o];
            #pragma unroll
            for (int c = 0; c < 8; ++c) x2 += cw[o * 8 + c] * xin[c][j];
            outj[j] = gelu_fast(x1 + x2);
        }
        *(float4*)&x[(size_t)(b * 8 + o) * 262144 + sp] =
            make_float4(outj[0], outj[1], outj[2], outj[3]);
        if (o < 4) {
            #pragma unroll
            for (int j = 0; j < 4; ++j) vbuf[(o * 16 + dyl) * 65 + wq * 4 + j] = outj[j];
        } else {
            #pragma unroll
            for (int j = 0; j < 4; ++j) valhi[o - 4][j] = outj[j];
        }
    }
    const int to = t >> 6, tdyl = (t >> 2) & 15, tkz = t & 3;
    __syncthreads();
    {   // A-DFT tail, channels 0..3
        float ar = 0.f, ai = 0.f; int ti = 0;
        const float* vr = &vbuf[(to * 16 + tdyl) * 65];
        for (int w = 0; w < 64; ++w) {
            float v = vr[w];
            ar += v * twc[ti]; ai -= v * tws[ti];
            ti = (ti + tkz) & 63;
        }
        A[((size_t)(b * 8 + to) * 4096 + dx * 64 + dy0 + tdyl) * 4 + tkz] =
            make_float2(ar, ai);
    }
    __syncthreads();
    #pragma unroll
    for (int oo = 0; oo < 4; ++oo)
        #pragma unroll
        for (int j = 0; j < 4; ++j)
            vbuf[(oo * 16 + dyl) * 65 + wq * 4 + j] = valhi[oo][j];
    __syncthreads();
    {   // A-DFT tail, channels 4..7
        float ar = 0.f, ai = 0.f; int ti = 0;
        const float* vr = &vbuf[(to * 16 + tdyl) * 65];
        for (int w = 0; w < 64; ++w) {
            float v = vr[w];
            ar += v * twc[ti]; ai -= v * tws[ti];
            ti = (ti + tkz) & 63;
        }
        A[((size_t)(b * 8 + 4 + to) * 4096 + dx * 64 + dy0 + tdyl) * 4 + tkz] =
            make_float2(ar, ai);
    }
}

// ---------------------------------------------------------------------------
// Layer 3: inverse DFT + conv (no gelu) -> fc1+gelu+fc2, + hard core u*nu.
// Weights read via wave-uniform global loads (SGPR), no LDS staging.
// ---------------------------------------------------------------------------
__global__ __launch_bounds__(256) void k_ptout(
    const float* __restrict__ x, const float2* __restrict__ O,
    const float* __restrict__ cw, const float* __restrict__ cb,
    const float* __restrict__ u, const float* __restrict__ nu,
    const float* __restrict__ fc1w, const float* __restrict__ fc1b,
    const float* __restrict__ fc2w, const float* __restrict__ fc2b,
    float* __restrict__ out)
{
    BUILD_TW();
    __shared__ float2 Ps[256];
    __shared__ float2 Qs[8 * 16 * 4];
    const int t = threadIdx.x, bid = blockIdx.x;
    const int b = bid >> 8, dx = (bid >> 2) & 63, dy0 = (bid & 3) * 16;
    __syncthreads();
    {
        int kz = t & 3, ky = (t >> 2) & 7, o = t >> 5;
        float re = 0.f, im = 0.f;
        #pragma unroll
        for (int kxi = 0; kxi < 8; ++kxi) {
            int kxv = kxi < 4 ? kxi : kxi + 56;
            int ti = (kxv * dx) & 63;
            float2 v = O[(((size_t)(b * 8 + o) * 8 + kxi) * 8 + ky) * 4 + kz];
            float cc = twc[ti], ss = tws[ti];
            re += v.x * cc - v.y * ss;
            im += v.y * cc + v.x * ss;
        }
        Ps[t] = make_float2(re, im);
    }
    __syncthreads();
    for (int it = t; it < 512; it += 256) {
        int kz = it & 3, dyl = (it >> 2) & 15, o = it >> 6;
        int dy = dy0 + dyl;
        float re = 0.f, im = 0.f;
        #pragma unroll
        for (int kyi = 0; kyi < 8; ++kyi) {
            int kyv = kyi < 4 ? kyi : kyi + 56;
            int ti = (kyv * dy) & 63;
            float2 v = Ps[(o * 8 + kyi) * 4 + kz];
            float cc = twc[ti], ss = tws[ti];
            re += v.x * cc - v.y * ss;
            im += v.y * cc + v.x * ss;
        }
        Qs[(o * 16 + dyl) * 4 + kz] = make_float2(re, im);
    }
    __syncthreads();
    const int dyl = t >> 4, wq = t & 15;
    const size_t sp = (size_t)dx * 4096 + (size_t)(dy0 + dyl) * 64 + wq * 4;
    float c1[4], s1[4], c2[4], s2[4], c3[4], s3[4];
    #pragma unroll
    for (int j = 0; j < 4; ++j) {
        int w = wq * 4 + j;
        c1[j] = twc[w];             s1[j] = tws[w];
        c2[j] = twc[(2 * w) & 63];  s2[j] = tws[(2 * w) & 63];
        c3[j] = twc[(3 * w) & 63];  s3[j] = tws[(3 * w) & 63];
    }
    float xin[8][4];
    #pragma unroll
    for (int c = 0; c < 8; ++c) {
        float4 v = *(const float4*)&x[(size_t)(b * 8 + c) * 262144 + sp];
        xin[c][0] = v.x; xin[c][1] = v.y; xin[c][2] = v.z; xin[c][3] = v.w;
    }
    const float invN3 = 1.0f / 262144.0f;
    float vv[8][4];   // layer-3 activations (no gelu)
    #pragma unroll
    for (int o = 0; o < 8; ++o) {
        float4 qa = *(const float4*)&Qs[(o * 16 + dyl) * 4];
        float4 qb = *(const float4*)&Qs[(o * 16 + dyl) * 4 + 2];
        #pragma unroll
        for (int j = 0; j < 4; ++j) {
            float x1 = qa.x + 2.f * (qa.z * c1[j] - qa.w * s1[j]
                                   + qb.x * c2[j] - qb.y * s2[j]
                                   + qb.z * c3[j] - qb.w * s3[j]);
            x1 *= invN3;
            float x2 = cb[o];
            #pragma unroll
            for (int c = 0; c < 8; ++c) x2 += cw[o * 8 + c] * xin[c][j];
            vv[o][j] = x1 + x2;
        }
    }
    float so[6][4];
    #pragma unroll
    for (int c6 = 0; c6 < 6; ++c6)
        #pragma unroll
        for (int j = 0; j < 4; ++j) so[c6][j] = fc2b[c6];
    #pragma unroll 4
    for (int h = 0; h < 32; ++h) {
        float wr[8];
        #pragma unroll
        for (int c = 0; c < 8; ++c) wr[c] = fc1w[h * 8 + c];   // uniform -> SGPR
        const float hb = fc1b[h];
        float w2r[6];
        #pragma unroll
        for (int c6 = 0; c6 < 6; ++c6) w2r[c6] = fc2w[c6 * 32 + h];
        #pragma unroll
        for (int j = 0; j < 4; ++j) {
            float a = hb;
            #pragma unroll
            for (int c = 0; c < 8; ++c) a += vv[c][j] * wr[c];
            float g = gelu_fast(a);
            #pragma unroll
            for (int c6 = 0; c6 < 6; ++c6) so[c6][j] += g * w2r[c6];
        }
    }
    const float nuv = nu[0];
    #pragma unroll
    for (int c6 = 0; c6 < 6; ++c6) {
        float4 res;
        float* rp = &res.x;
        if (c6 < 3) {
            float4 uu = *(const float4*)&u[(size_t)(b * 3 + c6) * 262144 + sp];
            const float* up = &uu.x;
            #pragma unroll
            for (int j = 0; j < 4; ++j) rp[j] = 0.3f * so[c6][j] + up[j] * nuv;
        } else {
            #pragma unroll
            for (int j = 0; j < 4; ++j) rp[j] = 0.3f * so[c6][j];
        }
        *(float4*)&out[(size_t)(b * 6 + c6) * 262144 + sp] = res;
    }
}

// pack split re/im spectral leaves into interleaved float2 (n_in==48 path)
__global__ void k_pack(const float* __restrict__ re, const float* __restrict__ im,
                       float2* __restrict__ dst)
{
    int i = blockIdx.x * 256 + threadIdx.x;
    if (i < 4096) dst[i] = make_float2(re[i], im[i]);
}

// ---------------------------------------------------------------------------
extern "C" void kernel_launch(void* const* d_in, const int* in_sizes, int n_in,
                              void* d_out, int out_size, void* d_ws, size_t ws_size,
                              hipStream_t stream)
{
    (void)out_size;
    const char* leaf[32];
    bool spec_split = false;
    const char* spec_re[16]; const char* spec_im[16];
    int src = 0;
    leaf[0] = (const char*)d_in[src++];
    leaf[1] = (const char*)d_in[src++];
    leaf[2] = (const char*)d_in[src++];
    leaf[3] = (const char*)d_in[src++];
    {
        int s = (src < n_in) ? in_sizes[src] : 4096;
        if (n_in >= 48 && s == 4096) {
            spec_split = true;
            for (int i = 0; i < 16; ++i) {
                spec_re[i] = (const char*)d_in[src++];
                spec_im[i] = (const char*)d_in[src++];
            }
        } else {
            int per;
            if (s == 4096 || s == 8192) per = 1;
            else if (s == 16384 || s == 32768) per = 4;
            else per = 16;
            for (int i = 0; i < 16; i += per) {
                const char* base = (const char*)d_in[src++];
                for (int j = 0; j < per; ++j) leaf[4 + i + j] = base + (size_t)j * 4096 * 8;
            }
        }
    }
    {
        int s = (src < n_in) ? in_sizes[src] : 64;
        if (s == 64) { for (int i = 0; i < 4; ++i) leaf[20 + i] = (const char*)d_in[src++]; }
        else { const char* base = (const char*)d_in[src++];
               for (int i = 0; i < 4; ++i) leaf[20 + i] = base + (size_t)i * 64 * 4; }
    }
    {
        int s = (src < n_in) ? in_sizes[src] : 8;
        if (s == 8) { for (int i = 0; i < 4; ++i) leaf[24 + i] = (const char*)d_in[src++]; }
        else { const char* base = (const char*)d_in[src++];
               for (int i = 0; i < 4; ++i) leaf[24 + i] = base + (size_t)i * 8 * 4; }
    }
    leaf[28] = (const char*)d_in[src++];
    leaf[29] = (const char*)d_in[src++];
    leaf[30] = (const char*)d_in[src++];
    leaf[31] = (const char*)d_in[src++];

    const float* u    = (const float*)leaf[0];
    const float* nu   = (const float*)leaf[1];
    const float* fc0w = (const float*)leaf[2];
    const float* fc0b = (const float*)leaf[3];
    const float* convw[4], *convb[4];
    for (int i = 0; i < 4; ++i) { convw[i] = (const float*)leaf[20 + i];
                                  convb[i] = (const float*)leaf[24 + i]; }
    const float* fc1w = (const float*)leaf[28];
    const float* fc1b = (const float*)leaf[29];
    const float* fc2w = (const float*)leaf[30];
    const float* fc2b = (const float*)leaf[31];

    const size_t szX = 67108864, szA = 8388608, szC = 131072,
                 szO = 131072, szSP = 524288;
    char* ws = (char*)d_ws;
    float* xbuf = (float*)ws;
    float2 *Abuf, *Cbuf, *Obuf, *SP;
    if (ws_size >= szX + szA + szC + szO + szSP) {
        Abuf = (float2*)(ws + szX);
        Cbuf = (float2*)(ws + szX + szA);
        Obuf = (float2*)(ws + szX + szA + szC);
        SP   = (float2*)(ws + szX + szA + szC + szO);
    } else {
        Obuf = (float2*)(ws + szX);
        Abuf = (float2*)d_out;
        Cbuf = (float2*)((char*)d_out + szA);
        SP   = (float2*)((char*)d_out + szA + szC);
    }

    const float2* specw[16];
    if (spec_split) {
        for (int i = 0; i < 16; ++i) {
            hipLaunchKernelGGL(k_pack, dim3(16), dim3(256), 0, stream,
                               (const float*)spec_re[i], (const float*)spec_im[i],
                               SP + (size_t)i * 4096);
            specw[i] = SP + (size_t)i * 4096;
        }
    } else {
        for (int i = 0; i < 16; ++i) specw[i] = (const float2*)leaf[4 + i];
    }
    float* outp = (float*)d_out;

    hipLaunchKernelGGL(k_liftA, dim3(2048), dim3(256), 0, stream, u, fc0w, fc0b, xbuf, Abuf);
    for (int L = 0; L < 4; ++L) {
        hipLaunchKernelGGL(k_head, dim3(64), dim3(256), 0, stream, Abuf, Cbuf);
        hipLaunchKernelGGL(k_mix, dim3(64), dim3(256), 0, stream,
                           Cbuf, specw[L*4+0], specw[L*4+1], specw[L*4+2], specw[L*4+3], Obuf);
        if (L < 3) {
            hipLaunchKernelGGL(k_ptA, dim3(2048), dim3(256), 0, stream,
                               xbuf, Obuf, convw[L], convb[L], Abuf);
        } else {
            hipLaunchKernelGGL(k_ptout, dim3(2048), dim3(256), 0, stream,
                               xbuf, Obuf, convw[3], convb[3], u, nu,
                               fc1w, fc1b, fc2w, fc2b, outp);
        }
    }
}

// Round 6
// 306.668 us; speedup vs baseline: 1.7476x; 1.2597x over previous
//
#include <hip/hip_runtime.h>

// FNO3d forward, MI355X. Round 6:
//  - k_ptA/k_liftA: A-DFT tail via 16-lane shfl_xor butterfly (no vbuf LDS,
//    no extra barriers); x/O prefetched at kernel top.
//  - k_head split: k_fH (512 blocks) + k_fDmix (D-DFT + mix, C stays in LDS).
//
// Layouts:
//   x  : float [B=8][C=8][64][64][64]          (67,108,864 B)
//   A  : float2[8][8][dx=64][dy=64][kz=4]      ( 8,388,608 B)
//   Bh : float2[8][8][dx=64][ky=8][kz=4]       ( 1,048,576 B)
//   O  : float2[8][8][kx=8][ky=8][kz=4]        (   131,072 B)

#define TWO_PI_OVER_64 0.09817477042468103

__device__ __forceinline__ float gelu_fast(float x) {
    float x2 = x * x;
    float p  = x * (1.0f + 0.044715f * x2);
    float e  = __builtin_amdgcn_exp2f(-2.3022083f * p);
    return x * __builtin_amdgcn_rcpf(1.0f + e);
}

#define BUILD_TW() \
    __shared__ float twc[64], tws[64]; \
    if (threadIdx.x < 64) { \
        double a_ = TWO_PI_OVER_64 * (double)threadIdx.x; \
        twc[threadIdx.x] = (float)cos(a_); tws[threadIdx.x] = (float)sin(a_); \
    }

// A-tail: partial W-DFT over this lane's 4 w-points, butterfly-reduce across
// the 16 wq-lanes, predicated float4 store (lane wq=0 -> kz0/1, wq=1 -> kz2/3).
__device__ __forceinline__ void a_tail_store(
    const float v[4], const float c1[4], const float s1[4],
    const float c2[4], const float s2[4], const float c3[4], const float s3[4],
    int wq, float2* __restrict__ Arow)
{
    float p0  = v[0] + v[1] + v[2] + v[3];
    float ar1 = v[0]*c1[0] + v[1]*c1[1] + v[2]*c1[2] + v[3]*c1[3];
    float ai1 = -(v[0]*s1[0] + v[1]*s1[1] + v[2]*s1[2] + v[3]*s1[3]);
    float ar2 = v[0]*c2[0] + v[1]*c2[1] + v[2]*c2[2] + v[3]*c2[3];
    float ai2 = -(v[0]*s2[0] + v[1]*s2[1] + v[2]*s2[2] + v[3]*s2[3]);
    float ar3 = v[0]*c3[0] + v[1]*c3[1] + v[2]*c3[2] + v[3]*c3[3];
    float ai3 = -(v[0]*s3[0] + v[1]*s3[1] + v[2]*s3[2] + v[3]*s3[3]);
    #pragma unroll
    for (int m = 1; m < 16; m <<= 1) {
        p0  += __shfl_xor(p0,  m);
        ar1 += __shfl_xor(ar1, m);  ai1 += __shfl_xor(ai1, m);
        ar2 += __shfl_xor(ar2, m);  ai2 += __shfl_xor(ai2, m);
        ar3 += __shfl_xor(ar3, m);  ai3 += __shfl_xor(ai3, m);
    }
    if (wq < 2) {
        float4 av;
        av.x = (wq == 0) ? p0   : ar2;
        av.y = (wq == 0) ? 0.f  : ai2;
        av.z = (wq == 0) ? ar1  : ar3;
        av.w = (wq == 0) ? ai1  : ai3;
        *((float4*)Arow + wq) = av;
    }
}

// ---------------------------------------------------------------------------
// Lift (3->8 ch) + forward W-DFT (shuffle tail).
// grid 2048 = b(8)*dx(64)*dyq(4); block 256 (dyl = t>>4, wq = t&15).
// ---------------------------------------------------------------------------
__global__ __launch_bounds__(256) void k_liftA(
    const float* __restrict__ u, const float* __restrict__ fc0w,
    const float* __restrict__ fc0b, float* __restrict__ x,
    float2* __restrict__ A)
{
    BUILD_TW();
    const int t = threadIdx.x, bid = blockIdx.x;
    const int b = bid >> 8, dx = (bid >> 2) & 63, dy0 = (bid & 3) * 16;
    const int dyl = t >> 4, wq = t & 15;
    const size_t sp = (size_t)dx * 4096 + (size_t)(dy0 + dyl) * 64 + wq * 4;
    float uin[3][4];
    #pragma unroll
    for (int c = 0; c < 3; ++c) {
        float4 v = *(const float4*)&u[(size_t)(b * 3 + c) * 262144 + sp];
        uin[c][0] = v.x; uin[c][1] = v.y; uin[c][2] = v.z; uin[c][3] = v.w;
    }
    __syncthreads();
    float c1[4], s1[4], c2[4], s2[4], c3[4], s3[4];
    #pragma unroll
    for (int j = 0; j < 4; ++j) {
        int w = wq * 4 + j;
        c1[j] = twc[w];             s1[j] = tws[w];
        c2[j] = twc[(2 * w) & 63];  s2[j] = tws[(2 * w) & 63];
        c3[j] = twc[(3 * w) & 63];  s3[j] = tws[(3 * w) & 63];
    }
    #pragma unroll
    for (int o = 0; o < 8; ++o) {
        float w0 = fc0w[o * 3 + 0], w1 = fc0w[o * 3 + 1], w2 = fc0w[o * 3 + 2];
        float bb = fc0b[o];
        float v[4];
        #pragma unroll
        for (int j = 0; j < 4; ++j)
            v[j] = bb + uin[0][j] * w0 + uin[1][j] * w1 + uin[2][j] * w2;
        *(float4*)&x[(size_t)(b * 8 + o) * 262144 + sp] =
            make_float4(v[0], v[1], v[2], v[3]);
        a_tail_store(v, c1, s1, c2, s2, c3, s3, wq,
                     A + ((size_t)(b * 8 + o) * 4096 + dx * 64 + dy0 + dyl) * 4);
    }
}

// ---------------------------------------------------------------------------
// H-axis DFT: A[b,c,dx,dy,kz] -> Bh[b,c,dx,ky,kz]. grid 512, block 256.
// One output per thread (131072 outputs), 64-iter dy loop.
// ---------------------------------------------------------------------------
__global__ __launch_bounds__(256) void k_fH(const float2* __restrict__ A,
                                            float2* __restrict__ Bh)
{
    BUILD_TW();
    __syncthreads();
    const int g = blockIdx.x * 256 + threadIdx.x;
    const int triple = g >> 5, idx = g & 31;
    const int ky = idx >> 2, kz = idx & 3;
    const int b = triple >> 9, c = (triple >> 6) & 7, dx = triple & 63;
    const int kyv = ky < 4 ? ky : ky + 56;
    const float2* Ap = A + (size_t)(b * 8 + c) * 16384 + dx * 256 + kz;
    float re = 0.f, im = 0.f;
    int ti = 0;
    #pragma unroll 8
    for (int dy = 0; dy < 64; ++dy) {
        float2 a = Ap[dy * 4];
        float cc = twc[ti], ss = tws[ti];
        re += a.x * cc + a.y * ss;   // * e^{-i phi}
        im += a.y * cc - a.x * ss;
        ti = (ti + kyv) & 63;
    }
    Bh[(size_t)(b * 8 + c) * 2048 + dx * 32 + ky * 4 + kz] = make_float2(re, im);
}

// ---------------------------------------------------------------------------
// D-axis DFT (into LDS) + spectral mix. grid 64 = b(8)*kx(8); block 256.
// Phase 1: thread (c,ky,kz) sums over dx -> Cs. Phase 2: thread (o,ky,kz)
// mixes channels with the corner weights, writes O.
// ---------------------------------------------------------------------------
__global__ __launch_bounds__(256) void k_fDmix(
    const float2* __restrict__ Bh,
    const float2* __restrict__ w1, const float2* __restrict__ w2,
    const float2* __restrict__ w3, const float2* __restrict__ w4,
    float2* __restrict__ O)
{
    BUILD_TW();
    __shared__ float2 Cs[256];   // [c][ky][kz] = c*32 + ky*4 + kz
    const int t = threadIdx.x, bid = blockIdx.x;
    const int b = bid >> 3, kx = bid & 7;
    const int kxv = kx < 4 ? kx : kx + 56;
    __syncthreads();
    {
        int kz = t & 3, ky = (t >> 2) & 7, c = t >> 5;
        const float2* Bp = Bh + (size_t)(b * 8 + c) * 2048 + ky * 4 + kz;
        float re = 0.f, im = 0.f;
        int ti = 0;
        #pragma unroll 8
        for (int dx = 0; dx < 64; ++dx) {
            float2 v = Bp[dx * 32];
            float cc = twc[ti], ss = tws[ti];
            re += v.x * cc + v.y * ss;
            im += v.y * cc - v.x * ss;
            ti = (ti + kxv) & 63;
        }
        Cs[t] = make_float2(re, im);
    }
    __syncthreads();
    {
        int kz = t & 3, ky = (t >> 2) & 7, o = t >> 5;
        const float2* wsel = (kx < 4) ? ((ky < 4) ? w1 : w3) : ((ky < 4) ? w2 : w4);
        int kxw = kx & 3, kyw = ky & 3;
        float re = 0.f, im = 0.f;
        #pragma unroll
        for (int i = 0; i < 8; ++i) {
            float2 cv = Cs[i * 32 + ky * 4 + kz];
            float2 wv = wsel[(((size_t)(i * 8 + o) * 4 + kxw) * 4 + kyw) * 4 + kz];
            re += cv.x * wv.x - cv.y * wv.y;
            im += cv.x * wv.y + cv.y * wv.x;
        }
        O[(((size_t)(b * 8 + o) * 8 + kx) * 8 + ky) * 4 + kz] = make_float2(re, im);
    }
}

// ---------------------------------------------------------------------------
// Inverse D/H DFT in LDS + irfftW + conv + gelu + x in place + next-layer A.
// x and O prefetched at kernel top. grid 2048; block 256.
// ---------------------------------------------------------------------------
__global__ __launch_bounds__(256, 4) void k_ptA(
    float* __restrict__ x, const float2* __restrict__ O,
    const float* __restrict__ cw, const float* __restrict__ cb,
    float2* __restrict__ A)
{
    BUILD_TW();
    __shared__ float2 Ps[256];          // [o][ky][kz]
    __shared__ float2 Qs[8 * 16 * 4];   // [o][dyl][kz]
    const int t = threadIdx.x, bid = blockIdx.x;
    const int b = bid >> 8, dx = (bid >> 2) & 63, dy0 = (bid & 3) * 16;
    const int dyl = t >> 4, wq = t & 15;
    const size_t sp = (size_t)dx * 4096 + (size_t)(dy0 + dyl) * 64 + wq * 4;
    // ---- prefetch: all global loads issued before any barrier ----
    float4 xv[8];
    #pragma unroll
    for (int c = 0; c < 8; ++c)
        xv[c] = *(const float4*)&x[(size_t)(b * 8 + c) * 262144 + sp];
    const int pkz = t & 3, pky = (t >> 2) & 7, po = t >> 5;
    float2 ov[8];
    #pragma unroll
    for (int kxi = 0; kxi < 8; ++kxi)
        ov[kxi] = O[(((size_t)(b * 8 + po) * 8 + kxi) * 8 + pky) * 4 + pkz];
    __syncthreads();
    {   // Ps
        float re = 0.f, im = 0.f;
        #pragma unroll
        for (int kxi = 0; kxi < 8; ++kxi) {
            int kxv = kxi < 4 ? kxi : kxi + 56;
            int ti = (kxv * dx) & 63;
            float cc = twc[ti], ss = tws[ti];
            re += ov[kxi].x * cc - ov[kxi].y * ss;   // * e^{+i phi}
            im += ov[kxi].y * cc + ov[kxi].x * ss;
        }
        Ps[t] = make_float2(re, im);
    }
    __syncthreads();
    for (int it = t; it < 512; it += 256) {  // Qs
        int kz = it & 3, qdyl = (it >> 2) & 15, o = it >> 6;
        int dy = dy0 + qdyl;
        float re = 0.f, im = 0.f;
        #pragma unroll
        for (int kyi = 0; kyi < 8; ++kyi) {
            int kyv = kyi < 4 ? kyi : kyi + 56;
            int ti = (kyv * dy) & 63;
            float2 v = Ps[(o * 8 + kyi) * 4 + kz];
            float cc = twc[ti], ss = tws[ti];
            re += v.x * cc - v.y * ss;
            im += v.y * cc + v.x * ss;
        }
        Qs[(o * 16 + qdyl) * 4 + kz] = make_float2(re, im);
    }
    __syncthreads();
    float c1[4], s1[4], c2[4], s2[4], c3[4], s3[4];
    #pragma unroll
    for (int j = 0; j < 4; ++j) {
        int w = wq * 4 + j;
        c1[j] = twc[w];             s1[j] = tws[w];
        c2[j] = twc[(2 * w) & 63];  s2[j] = tws[(2 * w) & 63];
        c3[j] = twc[(3 * w) & 63];  s3[j] = tws[(3 * w) & 63];
    }
    const float invN3 = 1.0f / 262144.0f;
    #pragma unroll
    for (int o = 0; o < 8; ++o) {
        float4 qa = *(const float4*)&Qs[(o * 16 + dyl) * 4];      // q0,q1
        float4 qb = *(const float4*)&Qs[(o * 16 + dyl) * 4 + 2];  // q2,q3
        float outj[4];
        #pragma unroll
        for (int j = 0; j < 4; ++j) {
            float x1 = qa.x + 2.f * (qa.z * c1[j] - qa.w * s1[j]
                                   + qb.x * c2[j] - qb.y * s2[j]
                                   + qb.z * c3[j] - qb.w * s3[j]);
            x1 *= invN3;
            float x2 = cb[o];
            #pragma unroll
            for (int c = 0; c < 8; ++c) {
                const float* xc = &xv[c].x;
                x2 += cw[o * 8 + c] * xc[j];
            }
            outj[j] = gelu_fast(x1 + x2);
        }
        *(float4*)&x[(size_t)(b * 8 + o) * 262144 + sp] =
            make_float4(outj[0], outj[1], outj[2], outj[3]);
        a_tail_store(outj, c1, s1, c2, s2, c3, s3, wq,
                     A + ((size_t)(b * 8 + o) * 4096 + dx * 64 + dy0 + dyl) * 4);
    }
}

// ---------------------------------------------------------------------------
// Layer 3: inverse DFT + conv (no gelu) -> fc1+gelu+fc2, + hard core u*nu.
// Writes d_out only; x/u prefetched at top.
// ---------------------------------------------------------------------------
__global__ __launch_bounds__(256, 4) void k_ptout(
    const float* __restrict__ x, const float2* __restrict__ O,
    const float* __restrict__ cw, const float* __restrict__ cb,
    const float* __restrict__ u, const float* __restrict__ nu,
    const float* __restrict__ fc1w, const float* __restrict__ fc1b,
    const float* __restrict__ fc2w, const float* __restrict__ fc2b,
    float* __restrict__ out)
{
    BUILD_TW();
    __shared__ float2 Ps[256];
    __shared__ float2 Qs[8 * 16 * 4];
    const int t = threadIdx.x, bid = blockIdx.x;
    const int b = bid >> 8, dx = (bid >> 2) & 63, dy0 = (bid & 3) * 16;
    const int dyl = t >> 4, wq = t & 15;
    const size_t sp = (size_t)dx * 4096 + (size_t)(dy0 + dyl) * 64 + wq * 4;
    float4 xv[8];
    #pragma unroll
    for (int c = 0; c < 8; ++c)
        xv[c] = *(const float4*)&x[(size_t)(b * 8 + c) * 262144 + sp];
    float4 uv[3];
    #pragma unroll
    for (int c = 0; c < 3; ++c)
        uv[c] = *(const float4*)&u[(size_t)(b * 3 + c) * 262144 + sp];
    const int pkz = t & 3, pky = (t >> 2) & 7, po = t >> 5;
    float2 ovv[8];
    #pragma unroll
    for (int kxi = 0; kxi < 8; ++kxi)
        ovv[kxi] = O[(((size_t)(b * 8 + po) * 8 + kxi) * 8 + pky) * 4 + pkz];
    __syncthreads();
    {
        float re = 0.f, im = 0.f;
        #pragma unroll
        for (int kxi = 0; kxi < 8; ++kxi) {
            int kxv = kxi < 4 ? kxi : kxi + 56;
            int ti = (kxv * dx) & 63;
            float cc = twc[ti], ss = tws[ti];
            re += ovv[kxi].x * cc - ovv[kxi].y * ss;
            im += ovv[kxi].y * cc + ovv[kxi].x * ss;
        }
        Ps[t] = make_float2(re, im);
    }
    __syncthreads();
    for (int it = t; it < 512; it += 256) {
        int kz = it & 3, qdyl = (it >> 2) & 15, o = it >> 6;
        int dy = dy0 + qdyl;
        float re = 0.f, im = 0.f;
        #pragma unroll
        for (int kyi = 0; kyi < 8; ++kyi) {
            int kyv = kyi < 4 ? kyi : kyi + 56;
            int ti = (kyv * dy) & 63;
            float2 v = Ps[(o * 8 + kyi) * 4 + kz];
            float cc = twc[ti], ss = tws[ti];
            re += v.x * cc - v.y * ss;
            im += v.y * cc + v.x * ss;
        }
        Qs[(o * 16 + qdyl) * 4 + kz] = make_float2(re, im);
    }
    __syncthreads();
    float c1[4], s1[4], c2[4], s2[4], c3[4], s3[4];
    #pragma unroll
    for (int j = 0; j < 4; ++j) {
        int w = wq * 4 + j;
        c1[j] = twc[w];             s1[j] = tws[w];
        c2[j] = twc[(2 * w) & 63];  s2[j] = tws[(2 * w) & 63];
        c3[j] = twc[(3 * w) & 63];  s3[j] = tws[(3 * w) & 63];
    }
    const float invN3 = 1.0f / 262144.0f;
    float vv[8][4];   // layer-3 activations (no gelu)
    #pragma unroll
    for (int o = 0; o < 8; ++o) {
        float4 qa = *(const float4*)&Qs[(o * 16 + dyl) * 4];
        float4 qb = *(const float4*)&Qs[(o * 16 + dyl) * 4 + 2];
        #pragma unroll
        for (int j = 0; j < 4; ++j) {
            float x1 = qa.x + 2.f * (qa.z * c1[j] - qa.w * s1[j]
                                   + qb.x * c2[j] - qb.y * s2[j]
                                   + qb.z * c3[j] - qb.w * s3[j]);
            x1 *= invN3;
            float x2 = cb[o];
            #pragma unroll
            for (int c = 0; c < 8; ++c) {
                const float* xc = &xv[c].x;
                x2 += cw[o * 8 + c] * xc[j];
            }
            vv[o][j] = x1 + x2;
        }
    }
    float so[6][4];
    #pragma unroll
    for (int c6 = 0; c6 < 6; ++c6)
        #pragma unroll
        for (int j = 0; j < 4; ++j) so[c6][j] = fc2b[c6];
    #pragma unroll 4
    for (int h = 0; h < 32; ++h) {
        float wr[8];
        #pragma unroll
        for (int c = 0; c < 8; ++c) wr[c] = fc1w[h * 8 + c];   // uniform -> SGPR
        const float hb = fc1b[h];
        float w2r[6];
        #pragma unroll
        for (int c6 = 0; c6 < 6; ++c6) w2r[c6] = fc2w[c6 * 32 + h];
        #pragma unroll
        for (int j = 0; j < 4; ++j) {
            float a = hb;
            #pragma unroll
            for (int c = 0; c < 8; ++c) a += vv[c][j] * wr[c];
            float g = gelu_fast(a);
            #pragma unroll
            for (int c6 = 0; c6 < 6; ++c6) so[c6][j] += g * w2r[c6];
        }
    }
    const float nuv = nu[0];
    #pragma unroll
    for (int c6 = 0; c6 < 6; ++c6) {
        float4 res;
        float* rp = &res.x;
        if (c6 < 3) {
            const float* up = &uv[c6].x;
            #pragma unroll
            for (int j = 0; j < 4; ++j) rp[j] = 0.3f * so[c6][j] + up[j] * nuv;
        } else {
            #pragma unroll
            for (int j = 0; j < 4; ++j) rp[j] = 0.3f * so[c6][j];
        }
        *(float4*)&out[(size_t)(b * 6 + c6) * 262144 + sp] = res;
    }
}

// pack split re/im spectral leaves into interleaved float2 (n_in==48 path)
__global__ void k_pack(const float* __restrict__ re, const float* __restrict__ im,
                       float2* __restrict__ dst)
{
    int i = blockIdx.x * 256 + threadIdx.x;
    if (i < 4096) dst[i] = make_float2(re[i], im[i]);
}

// ---------------------------------------------------------------------------
extern "C" void kernel_launch(void* const* d_in, const int* in_sizes, int n_in,
                              void* d_out, int out_size, void* d_ws, size_t ws_size,
                              hipStream_t stream)
{
    (void)out_size;
    const char* leaf[32];
    bool spec_split = false;
    const char* spec_re[16]; const char* spec_im[16];
    int src = 0;
    leaf[0] = (const char*)d_in[src++];
    leaf[1] = (const char*)d_in[src++];
    leaf[2] = (const char*)d_in[src++];
    leaf[3] = (const char*)d_in[src++];
    {
        int s = (src < n_in) ? in_sizes[src] : 4096;
        if (n_in >= 48 && s == 4096) {
            spec_split = true;
            for (int i = 0; i < 16; ++i) {
                spec_re[i] = (const char*)d_in[src++];
                spec_im[i] = (const char*)d_in[src++];
            }
        } else {
            int per;
            if (s == 4096 || s == 8192) per = 1;
            else if (s == 16384 || s == 32768) per = 4;
            else per = 16;
            for (int i = 0; i < 16; i += per) {
                const char* base = (const char*)d_in[src++];
                for (int j = 0; j < per; ++j) leaf[4 + i + j] = base + (size_t)j * 4096 * 8;
            }
        }
    }
    {
        int s = (src < n_in) ? in_sizes[src] : 64;
        if (s == 64) { for (int i = 0; i < 4; ++i) leaf[20 + i] = (const char*)d_in[src++]; }
        else { const char* base = (const char*)d_in[src++];
               for (int i = 0; i < 4; ++i) leaf[20 + i] = base + (size_t)i * 64 * 4; }
    }
    {
        int s = (src < n_in) ? in_sizes[src] : 8;
        if (s == 8) { for (int i = 0; i < 4; ++i) leaf[24 + i] = (const char*)d_in[src++]; }
        else { const char* base = (const char*)d_in[src++];
               for (int i = 0; i < 4; ++i) leaf[24 + i] = base + (size_t)i * 8 * 4; }
    }
    leaf[28] = (const char*)d_in[src++];
    leaf[29] = (const char*)d_in[src++];
    leaf[30] = (const char*)d_in[src++];
    leaf[31] = (const char*)d_in[src++];

    const float* u    = (const float*)leaf[0];
    const float* nu   = (const float*)leaf[1];
    const float* fc0w = (const float*)leaf[2];
    const float* fc0b = (const float*)leaf[3];
    const float* convw[4], *convb[4];
    for (int i = 0; i < 4; ++i) { convw[i] = (const float*)leaf[20 + i];
                                  convb[i] = (const float*)leaf[24 + i]; }
    const float* fc1w = (const float*)leaf[28];
    const float* fc1b = (const float*)leaf[29];
    const float* fc2w = (const float*)leaf[30];
    const float* fc2b = (const float*)leaf[31];

    // scratch: x | A | Bh | O | SP.  Fallback: A,Bh,SP in d_out (dead before
    // k_ptout writes it); O must stay in ws (live during k_ptout).
    const size_t szX = 67108864, szA = 8388608, szB = 1048576,
                 szO = 131072, szSP = 524288;
    char* ws = (char*)d_ws;
    float* xbuf = (float*)ws;
    float2 *Abuf, *Bbuf, *Obuf, *SP;
    if (ws_size >= szX + szA + szB + szO + szSP) {
        Abuf = (float2*)(ws + szX);
        Bbuf = (float2*)(ws + szX + szA);
        Obuf = (float2*)(ws + szX + szA + szB);
        SP   = (float2*)(ws + szX + szA + szB + szO);
    } else {
        Obuf = (float2*)(ws + szX);
        Abuf = (float2*)d_out;
        Bbuf = (float2*)((char*)d_out + szA);
        SP   = (float2*)((char*)d_out + szA + szB);
    }

    const float2* specw[16];
    if (spec_split) {
        for (int i = 0; i < 16; ++i) {
            hipLaunchKernelGGL(k_pack, dim3(16), dim3(256), 0, stream,
                               (const float*)spec_re[i], (const float*)spec_im[i],
                               SP + (size_t)i * 4096);
            specw[i] = SP + (size_t)i * 4096;
        }
    } else {
        for (int i = 0; i < 16; ++i) specw[i] = (const float2*)leaf[4 + i];
    }
    float* outp = (float*)d_out;

    hipLaunchKernelGGL(k_liftA, dim3(2048), dim3(256), 0, stream, u, fc0w, fc0b, xbuf, Abuf);
    for (int L = 0; L < 4; ++L) {
        hipLaunchKernelGGL(k_fH, dim3(512), dim3(256), 0, stream, Abuf, Bbuf);
        hipLaunchKernelGGL(k_fDmix, dim3(64), dim3(256), 0, stream,
                           Bbuf, specw[L*4+0], specw[L*4+1], specw[L*4+2], specw[L*4+3], Obuf);
        if (L < 3) {
            hipLaunchKernelGGL(k_ptA, dim3(2048), dim3(256), 0, stream,
                               xbuf, Obuf, convw[L], convb[L], Abuf);
        } else {
            hipLaunchKernelGGL(k_ptout, dim3(2048), dim3(256), 0, stream,
                               xbuf, Obuf, convw[3], convb[3], u, nu,
                               fc1w, fc1b, fc2w, fc2b, outp);
        }
    }
}